// Round 7
// baseline (167.811 us; speedup 1.0000x reference)
//
#include <hip/hip_runtime.h>
#include <stdint.h>

#define BB 4
#define NN 2048
#define FIN 256
#define FOUT 128
#define NH 4
#define NEG_SLOPE 0.2f

typedef short bf16x8 __attribute__((ext_vector_type(8)));
typedef unsigned short u16x8 __attribute__((ext_vector_type(8)));
typedef float f32x4 __attribute__((ext_vector_type(4)));
typedef unsigned long long u64;

__device__ inline float b2f(unsigned short u) {
    union { unsigned int i; float f; } x; x.i = ((unsigned int)u) << 16; return x.f;
}
__device__ inline unsigned short f2b(float f) {   // fp32 -> bf16 RNE
    union { float f; unsigned int i; } x; x.f = f;
    unsigned int r = x.i + 0x7fffu + ((x.i >> 16) & 1u);
    return (unsigned short)(r >> 16);
}
__device__ inline unsigned short f2b_fast(float f) {  // round-half-up (f >= 0 here)
    union { float f; unsigned int i; } x; x.f = f;
    return (unsigned short)((x.i + 0x8000u) >> 16);
}
union F16U { unsigned short u; _Float16 h; };
__device__ inline float f16lo(unsigned int v) { F16U x; x.u = (unsigned short)(v & 0xffffu); return (float)x.h; }
__device__ inline float f16hi(unsigned int v) { F16U x; x.u = (unsigned short)(v >> 16); return (float)x.h; }
__device__ inline unsigned int packf16(float a, float b) {
    F16U x, y; x.h = (_Float16)a; y.h = (_Float16)b;
    return (unsigned int)x.u | ((unsigned int)y.u << 16);
}

// ---------------------------------------------------------------------------
// kcvtW: split W fp32 -> bf16 hi/lo pair
// ---------------------------------------------------------------------------
__global__ __launch_bounds__(256) void kcvt_w(const float* __restrict__ Ww,
                                              unsigned short* __restrict__ Whi,
                                              unsigned short* __restrict__ Wlo) {
    int idx = blockIdx.x * 256 + threadIdx.x;   // 32768 elems
    float v = Ww[idx];
    unsigned short hb = f2b(v);
    Whi[idx] = hb;
    Wlo[idx] = f2b(v - b2f(hb));
}

// ---------------------------------------------------------------------------
// K1 (MFMA): Wh[16 rows][128 o] = h_tile @ W^T + b, split-bf16 (hh+hl+lh).
// Epilogue: WhT bf16 [b][o][n]; exp tables:
//   ELpair[b*4+h][i] = (exp(eL), exp(0.2 eL)) fp32x2
//   ERpk  [b][j][h]  = packf16(exp(eR), exp(0.2 eR))
// ---------------------------------------------------------------------------
__global__ __launch_bounds__(256) void k1_wh(
    const float* __restrict__ h, const unsigned short* __restrict__ Whi,
    const unsigned short* __restrict__ Wlo, const float* __restrict__ Wb,
    const float* __restrict__ attw, unsigned short* __restrict__ WhT,
    float2* __restrict__ ELpair, unsigned int* __restrict__ ERpk) {
    __shared__ unsigned short Ahi[16][264];
    __shared__ unsigned short Alo[16][264];
    __shared__ float whs[16][132];
    int t = threadIdx.x;
    int b = blockIdx.x >> 7;
    int n0 = (blockIdx.x & 127) * 16;
    {
        int r = t >> 4, c = (t & 15) * 16;
        const float* hp = h + ((size_t)(b * NN + n0 + r)) * FIN + c;
        u16x8 hi0, hi1, lo0, lo1;
        #pragma unroll
        for (int q = 0; q < 4; ++q) {
            float4 v = *(const float4*)(hp + q * 4);
            float vv[4] = {v.x, v.y, v.z, v.w};
            #pragma unroll
            for (int e = 0; e < 4; ++e) {
                int idx = q * 4 + e;
                unsigned short hb = f2b(vv[e]);
                unsigned short lb = f2b(vv[e] - b2f(hb));
                if (idx < 8) { hi0[idx] = (short)hb; lo0[idx] = (short)lb; }
                else         { hi1[idx - 8] = (short)hb; lo1[idx - 8] = (short)lb; }
            }
        }
        *(u16x8*)&Ahi[r][c] = *(u16x8*)&hi0;
        *(u16x8*)&Ahi[r][c + 8] = *(u16x8*)&hi1;
        *(u16x8*)&Alo[r][c] = *(u16x8*)&lo0;
        *(u16x8*)&Alo[r][c + 8] = *(u16x8*)&lo1;
    }
    __syncthreads();
    int lane = t & 63, wv = t >> 6;
    int m = lane & 15, quad = lane >> 4;
    int o0 = wv * 32;
    f32x4 acc0 = {0.f, 0.f, 0.f, 0.f}, acc1 = {0.f, 0.f, 0.f, 0.f};
    const unsigned short* wh0 = Whi + (size_t)(o0 + m) * FIN;
    const unsigned short* wl0 = Wlo + (size_t)(o0 + m) * FIN;
    const unsigned short* wh1 = Whi + (size_t)(o0 + 16 + m) * FIN;
    const unsigned short* wl1 = Wlo + (size_t)(o0 + 16 + m) * FIN;
    #pragma unroll
    for (int ks = 0; ks < 8; ++ks) {
        int ko = ks * 32 + quad * 8;
        bf16x8 ahi = *(bf16x8*)&Ahi[m][ko];
        bf16x8 alo = *(bf16x8*)&Alo[m][ko];
        bf16x8 bh0 = *(const bf16x8*)(wh0 + ko);
        bf16x8 bl0 = *(const bf16x8*)(wl0 + ko);
        bf16x8 bh1 = *(const bf16x8*)(wh1 + ko);
        bf16x8 bl1 = *(const bf16x8*)(wl1 + ko);
        acc0 = __builtin_amdgcn_mfma_f32_16x16x32_bf16(ahi, bh0, acc0, 0, 0, 0);
        acc0 = __builtin_amdgcn_mfma_f32_16x16x32_bf16(ahi, bl0, acc0, 0, 0, 0);
        acc0 = __builtin_amdgcn_mfma_f32_16x16x32_bf16(alo, bh0, acc0, 0, 0, 0);
        acc1 = __builtin_amdgcn_mfma_f32_16x16x32_bf16(ahi, bh1, acc1, 0, 0, 0);
        acc1 = __builtin_amdgcn_mfma_f32_16x16x32_bf16(ahi, bl1, acc1, 0, 0, 0);
        acc1 = __builtin_amdgcn_mfma_f32_16x16x32_bf16(alo, bh1, acc1, 0, 0, 0);
    }
    float bias0 = Wb[o0 + m], bias1 = Wb[o0 + 16 + m];
    #pragma unroll
    for (int reg = 0; reg < 4; ++reg) {
        int row = quad * 4 + reg;
        whs[row][o0 + m] = acc0[reg] + bias0;
        whs[row][o0 + 16 + m] = acc1[reg] + bias1;
    }
    __syncthreads();
    {   // WhT writer: 2 threads per o, 8 n each
        int o = t >> 1, half = t & 1;
        u16x8 v8;
        #pragma unroll
        for (int r = 0; r < 8; ++r) v8[r] = (short)f2b(whs[half * 8 + r][o]);
        *(u16x8*)(WhT + (size_t)(b * FOUT + o) * NN + n0 + half * 8) = v8;
    }
    {   // e-dots + exp tables
        int outi = t >> 1, half = t & 1;
        int i = outi >> 3, d = outi & 7, hh = d & 3, side = d >> 2;
        const float* arow = attw + hh * (2 * FOUT) + side * FOUT + half * 64;
        float s = 0.f;
        #pragma unroll 8
        for (int k = 0; k < 64; ++k) s = fmaf(whs[i][half * 64 + k], arow[k], s);
        s += __shfl_xor(s, 1);
        if (half == 0) {
            float p = __expf(s), n = __expf(NEG_SLOPE * s);
            if (side == 0) {
                ELpair[(size_t)(b * NH + hh) * NN + n0 + i] = make_float2(p, n);
            } else {
                ERpk[((size_t)b * NN + n0 + i) * NH + hh] = packf16(p, n);
            }
        }
    }
}

// ---------------------------------------------------------------------------
// k_pack: adj (N x N int32) -> bitmask (N rows x 32 u64). Pure HBM stream.
// ---------------------------------------------------------------------------
__global__ __launch_bounds__(256) void k_pack(const int* __restrict__ adj,
                                              u64* __restrict__ mask) {
    int row = blockIdx.x;
    int wave = threadIdx.x >> 6, lane = threadIdx.x & 63;
    #pragma unroll
    for (int it = 0; it < 8; ++it) {
        int w = it * 4 + wave;
        int j = w * 64 + lane;
        u64 m = __ballot(adj[(size_t)row * NN + j] != 0);
        if (lane == 0) mask[row * 32 + w] = m;
    }
}

// ---------------------------------------------------------------------------
// kstat: s[b,h,i] = sum_j bit(i,j)*max(elp_h(i)*erp_h(j), eln_h(i)*ern_h(j));
//   ELSC[b][i][h][2] = ELpair * 1/(4s)  (0 if empty row)
// Block (16 i, b); each WAVE owns 4 rows: EL consts in regs (uniform loads),
// mask words wave-uniform (scalar loads), ER coalesced uint4, 64x i-reuse.
// ---------------------------------------------------------------------------
__global__ __launch_bounds__(256) void kstat(
    const unsigned int* __restrict__ ERpk, const float2* __restrict__ ELpair,
    const u64* __restrict__ mask, float* __restrict__ ELSC) {
    int t = threadIdx.x, lane = t & 63, wv = t >> 6;
    int b = blockIdx.y;
    int i0 = blockIdx.x * 16 + wv * 4;     // this wave's 4 rows
    float elp[4][4], eln[4][4];            // [r][h], wave-uniform
    #pragma unroll
    for (int r = 0; r < 4; ++r)
        #pragma unroll
        for (int hh = 0; hh < 4; ++hh) {
            float2 e2 = ELpair[(size_t)(b * NH + hh) * NN + i0 + r];
            elp[r][hh] = e2.x; eln[r][hh] = e2.y;
        }
    float acc[4][4];
    #pragma unroll
    for (int r = 0; r < 4; ++r)
        #pragma unroll
        for (int hh = 0; hh < 4; ++hh) acc[r][hh] = 0.f;

    const uint4* erb = (const uint4*)(ERpk + (size_t)b * NN * NH);
    #pragma unroll 2
    for (int jc = 0; jc < 32; ++jc) {      // 64 j per chunk
        uint4 er4 = erb[jc * 64 + lane];
        float erp0 = f16lo(er4.x), ern0 = f16hi(er4.x);
        float erp1 = f16lo(er4.y), ern1 = f16hi(er4.y);
        float erp2 = f16lo(er4.z), ern2 = f16hi(er4.z);
        float erp3 = f16lo(er4.w), ern3 = f16hi(er4.w);
        #pragma unroll
        for (int r = 0; r < 4; ++r) {
            u64 mw = mask[(size_t)(i0 + r) * 32 + jc];   // wave-uniform -> s_load
            bool bit = (mw >> lane) & 1ull;
            acc[r][0] += bit ? fmaxf(elp[r][0] * erp0, eln[r][0] * ern0) : 0.f;
            acc[r][1] += bit ? fmaxf(elp[r][1] * erp1, eln[r][1] * ern1) : 0.f;
            acc[r][2] += bit ? fmaxf(elp[r][2] * erp2, eln[r][2] * ern2) : 0.f;
            acc[r][3] += bit ? fmaxf(elp[r][3] * erp3, eln[r][3] * ern3) : 0.f;
        }
    }
    // butterfly-reduce each of the 16 sums across the wave
    #pragma unroll
    for (int r = 0; r < 4; ++r)
        #pragma unroll
        for (int hh = 0; hh < 4; ++hh) {
            float v = acc[r][hh];
            #pragma unroll
            for (int off = 32; off; off >>= 1) v += __shfl_xor(v, off);
            acc[r][hh] = v;
        }
    if (lane < 16) {
        int r = lane >> 2, hh = lane & 3;
        float tot = acc[r][hh];
        float iv = (tot > 0.f) ? 1.f / (4.f * tot) : 0.f;
        float2 e2 = ELpair[(size_t)(b * NH + hh) * NN + i0 + r];
        float* dst = ELSC + ((size_t)b * NN + i0 + r) * 8 + hh * 2;
        dst[0] = e2.x * iv;
        dst[1] = e2.y * iv;
    }
}

// ---------------------------------------------------------------------------
// K2b: P[jhalf][b,i,o] = sum_{j in half} w[i,j] * Wh[b,j,o], MFMA 16x16x32.
// Block = 512 thr (8 waves), TI=64 i-rows, all 128 o, 1024 j (one half).
// ---------------------------------------------------------------------------
__global__ __launch_bounds__(512, 2) void k2b_mfma(
    const unsigned short* __restrict__ WhT, const unsigned int* __restrict__ ERpk,
    const float* __restrict__ ELSC, const u64* __restrict__ mask,
    float* __restrict__ P) {
    __shared__ unsigned short wt[64][264];    // 33.8 KB bf16 w-tile
    __shared__ u64 mws[64][16];               // 8 KB
    __shared__ float elsc_s[64][8];           // 2 KB
    int t = threadIdx.x;
    int b = blockIdx.y, i0 = blockIdx.x * 64, jhalf = blockIdx.z;
    int lane = t & 63, wv = t >> 6;
    int m = lane & 15, quad = lane >> 4;
    if (t < 128) {
        ((float4*)elsc_s)[t] = *(const float4*)(ELSC + ((size_t)b * NN + i0) * 8 + t * 4);
    }
    {
        int r = t >> 3, wp = (t & 7) * 2;
        *(ulonglong2*)&mws[r][wp] =
            *(const ulonglong2*)(mask + (size_t)(i0 + r) * 32 + jhalf * 16 + wp);
    }
    int r0 = wv * 8;
    int o0 = wv * 16;
    const unsigned short* bp = WhT + (size_t)(b * FOUT + o0 + m) * NN + jhalf * 1024;
    f32x4 acc[4];
    #pragma unroll
    for (int k = 0; k < 4; ++k) acc[k] = (f32x4){0.f, 0.f, 0.f, 0.f};

    for (int ch = 0; ch < 4; ++ch) {
        int j0 = ch * 256;
        __syncthreads();
        bf16x8 bfr[8];
        #pragma unroll
        for (int ks = 0; ks < 8; ++ks)
            bfr[ks] = *(const bf16x8*)(bp + j0 + ks * 32 + quad * 8);
        float erp[4][4], ern[4][4];
        #pragma unroll
        for (int q = 0; q < 4; ++q) {
            int jg = jhalf * 1024 + j0 + q * 64 + lane;
            uint4 er4 = *(const uint4*)(ERpk + ((size_t)b * NN + jg) * 4);
            erp[q][0] = f16lo(er4.x); ern[q][0] = f16hi(er4.x);
            erp[q][1] = f16lo(er4.y); ern[q][1] = f16hi(er4.y);
            erp[q][2] = f16lo(er4.z); ern[q][2] = f16hi(er4.z);
            erp[q][3] = f16lo(er4.w); ern[q][3] = f16hi(er4.w);
        }
        #pragma unroll
        for (int r = 0; r < 8; ++r) {
            int ir = r0 + r;
            float4 c0 = *(float4*)&elsc_s[ir][0];
            float4 c1 = *(float4*)&elsc_s[ir][4];
            u64 mwq[4] = {mws[ir][ch * 4 + 0], mws[ir][ch * 4 + 1],
                          mws[ir][ch * 4 + 2], mws[ir][ch * 4 + 3]};
            #pragma unroll
            for (int q = 0; q < 4; ++q) {
                float p = fmaxf(c0.x * erp[q][0], c0.y * ern[q][0]);
                p += fmaxf(c0.z * erp[q][1], c0.w * ern[q][1]);
                p += fmaxf(c1.x * erp[q][2], c1.y * ern[q][2]);
                p += fmaxf(c1.z * erp[q][3], c1.w * ern[q][3]);
                wt[ir][q * 64 + lane] = ((mwq[q] >> lane) & 1ull) ? f2b_fast(p) : 0;
            }
        }
        __syncthreads();
        #pragma unroll
        for (int isub = 0; isub < 4; ++isub) {
            #pragma unroll
            for (int ks = 0; ks < 8; ++ks) {
                bf16x8 a = *(bf16x8*)&wt[isub * 16 + m][ks * 32 + quad * 8];
                acc[isub] = __builtin_amdgcn_mfma_f32_16x16x32_bf16(a, bfr[ks], acc[isub], 0, 0, 0);
            }
        }
    }
    float* pb = P + (((size_t)jhalf * BB + b) * NN + i0) * FOUT;
    #pragma unroll
    for (int isub = 0; isub < 4; ++isub) {
        #pragma unroll
        for (int reg = 0; reg < 4; ++reg) {
            int row = isub * 16 + quad * 4 + reg;
            pb[(size_t)row * FOUT + o0 + m] = acc[isub][reg];
        }
    }
}

// ---------------------------------------------------------------------------
// K3: out = relu(P0 + P1)
// ---------------------------------------------------------------------------
__global__ __launch_bounds__(256) void k3_relu(const float* __restrict__ P,
                                               float* __restrict__ out) {
    int idx = blockIdx.x * 256 + threadIdx.x;
    float4 a = ((const float4*)P)[idx];
    float4 c = ((const float4*)P)[idx + (BB * NN * FOUT / 4)];
    a.x = fmaxf(a.x + c.x, 0.f); a.y = fmaxf(a.y + c.y, 0.f);
    a.z = fmaxf(a.z + c.z, 0.f); a.w = fmaxf(a.w + c.w, 0.f);
    ((float4*)out)[idx] = a;
}

extern "C" void kernel_launch(void* const* d_in, const int* in_sizes, int n_in,
                              void* d_out, int out_size, void* d_ws, size_t ws_size,
                              hipStream_t stream) {
    const float* h    = (const float*)d_in[0];
    const int* adj    = (const int*)d_in[1];
    const float* Ww   = (const float*)d_in[2];
    const float* Wb   = (const float*)d_in[3];
    const float* attw = (const float*)d_in[4];
    float* out = (float*)d_out;
    char* ws = (char*)d_ws;
    // workspace layout (11.8 MB)
    unsigned short* Whi = (unsigned short*)(ws);                 // 64 KB
    unsigned short* Wlo = (unsigned short*)(ws + 65536);         // 64 KB
    unsigned short* WhT = (unsigned short*)(ws + 131072);        // 2 MB [b][o][n] bf16
    float2*       ELpair = (float2*)(ws + 2228224);              // 256 KB [bh][i]
    unsigned int* ERpk   = (unsigned int*)(ws + 2490368);        // 128 KB [b][j][h] f16pk
    float*        ELSC   = (float*)(ws + 2621440);               // 256 KB [b][i][h][2]
    u64*          mask   = (u64*)(ws + 2883584);                 // 512 KB
    float*        P      = (float*)(ws + 3407872);               // 2 x 4 MB partials

    kcvt_w<<<dim3(128), dim3(256), 0, stream>>>(Ww, Whi, Wlo);
    k1_wh<<<dim3(BB * NN / 16), dim3(256), 0, stream>>>(h, Whi, Wlo, Wb, attw,
                                                        WhT, ELpair, ERpk);
    k_pack<<<dim3(NN), dim3(256), 0, stream>>>(adj, mask);
    kstat<<<dim3(NN / 16, BB), dim3(256), 0, stream>>>(ERpk, ELpair, mask, ELSC);
    k2b_mfma<<<dim3(NN / 64, BB, 2), dim3(512), 0, stream>>>(WhT, ERpk, ELSC, mask, P);
    k3_relu<<<dim3(BB * NN * FOUT / 1024), dim3(256), 0, stream>>>(P, out);
}

// Round 8
// 137.197 us; speedup vs baseline: 1.2231x; 1.2231x over previous
//
#include <hip/hip_runtime.h>
#include <stdint.h>

#define BB 4
#define NN 2048
#define FIN 256
#define FOUT 128
#define NH 4
#define NEG_SLOPE 0.2f

typedef short bf16x8 __attribute__((ext_vector_type(8)));
typedef unsigned short u16x8 __attribute__((ext_vector_type(8)));
typedef float f32x4 __attribute__((ext_vector_type(4)));
typedef unsigned long long u64;

__device__ inline float b2f(unsigned short u) {
    union { unsigned int i; float f; } x; x.i = ((unsigned int)u) << 16; return x.f;
}
__device__ inline unsigned short f2b(float f) {   // fp32 -> bf16 RNE
    union { float f; unsigned int i; } x; x.f = f;
    unsigned int r = x.i + 0x7fffu + ((x.i >> 16) & 1u);
    return (unsigned short)(r >> 16);
}
__device__ inline unsigned short f2b_fast(float f) {  // round-half-up (f >= 0 here)
    union { float f; unsigned int i; } x; x.f = f;
    return (unsigned short)((x.i + 0x8000u) >> 16);
}
union F16U { unsigned short u; _Float16 h; };
__device__ inline float f16lo(unsigned int v) { F16U x; x.u = (unsigned short)(v & 0xffffu); return (float)x.h; }
__device__ inline float f16hi(unsigned int v) { F16U x; x.u = (unsigned short)(v >> 16); return (float)x.h; }
__device__ inline unsigned int packf16(float a, float b) {
    F16U x, y; x.h = (_Float16)a; y.h = (_Float16)b;
    return (unsigned int)x.u | ((unsigned int)y.u << 16);
}

// ---------------------------------------------------------------------------
// kcvtW: split W fp32 -> bf16 hi/lo pair
// ---------------------------------------------------------------------------
__global__ __launch_bounds__(256) void kcvt_w(const float* __restrict__ Ww,
                                              unsigned short* __restrict__ Whi,
                                              unsigned short* __restrict__ Wlo) {
    int idx = blockIdx.x * 256 + threadIdx.x;   // 32768 elems
    float v = Ww[idx];
    unsigned short hb = f2b(v);
    Whi[idx] = hb;
    Wlo[idx] = f2b(v - b2f(hb));
}

// ---------------------------------------------------------------------------
// K1 (MFMA): Wh[16 rows][128 o] = h_tile @ W^T + b, split-bf16 (hh+hl+lh).
// Epilogue: WhT bf16 [b][o][n]; exp tables:
//   ELpair[b*4+h][i] = (exp(eL), exp(0.2 eL)) fp32x2
//   ERpk  [b][j][h]  = packf16(exp(eR), exp(0.2 eR))
// ---------------------------------------------------------------------------
__global__ __launch_bounds__(256) void k1_wh(
    const float* __restrict__ h, const unsigned short* __restrict__ Whi,
    const unsigned short* __restrict__ Wlo, const float* __restrict__ Wb,
    const float* __restrict__ attw, unsigned short* __restrict__ WhT,
    float2* __restrict__ ELpair, unsigned int* __restrict__ ERpk) {
    __shared__ unsigned short Ahi[16][264];
    __shared__ unsigned short Alo[16][264];
    __shared__ float whs[16][132];
    int t = threadIdx.x;
    int b = blockIdx.x >> 7;
    int n0 = (blockIdx.x & 127) * 16;
    {
        int r = t >> 4, c = (t & 15) * 16;
        const float* hp = h + ((size_t)(b * NN + n0 + r)) * FIN + c;
        u16x8 hi0, hi1, lo0, lo1;
        #pragma unroll
        for (int q = 0; q < 4; ++q) {
            float4 v = *(const float4*)(hp + q * 4);
            float vv[4] = {v.x, v.y, v.z, v.w};
            #pragma unroll
            for (int e = 0; e < 4; ++e) {
                int idx = q * 4 + e;
                unsigned short hb = f2b(vv[e]);
                unsigned short lb = f2b(vv[e] - b2f(hb));
                if (idx < 8) { hi0[idx] = (short)hb; lo0[idx] = (short)lb; }
                else         { hi1[idx - 8] = (short)hb; lo1[idx - 8] = (short)lb; }
            }
        }
        *(u16x8*)&Ahi[r][c] = *(u16x8*)&hi0;
        *(u16x8*)&Ahi[r][c + 8] = *(u16x8*)&hi1;
        *(u16x8*)&Alo[r][c] = *(u16x8*)&lo0;
        *(u16x8*)&Alo[r][c + 8] = *(u16x8*)&lo1;
    }
    __syncthreads();
    int lane = t & 63, wv = t >> 6;
    int m = lane & 15, quad = lane >> 4;
    int o0 = wv * 32;
    f32x4 acc0 = {0.f, 0.f, 0.f, 0.f}, acc1 = {0.f, 0.f, 0.f, 0.f};
    const unsigned short* wh0 = Whi + (size_t)(o0 + m) * FIN;
    const unsigned short* wl0 = Wlo + (size_t)(o0 + m) * FIN;
    const unsigned short* wh1 = Whi + (size_t)(o0 + 16 + m) * FIN;
    const unsigned short* wl1 = Wlo + (size_t)(o0 + 16 + m) * FIN;
    #pragma unroll
    for (int ks = 0; ks < 8; ++ks) {
        int ko = ks * 32 + quad * 8;
        bf16x8 ahi = *(bf16x8*)&Ahi[m][ko];
        bf16x8 alo = *(bf16x8*)&Alo[m][ko];
        bf16x8 bh0 = *(const bf16x8*)(wh0 + ko);
        bf16x8 bl0 = *(const bf16x8*)(wl0 + ko);
        bf16x8 bh1 = *(const bf16x8*)(wh1 + ko);
        bf16x8 bl1 = *(const bf16x8*)(wl1 + ko);
        acc0 = __builtin_amdgcn_mfma_f32_16x16x32_bf16(ahi, bh0, acc0, 0, 0, 0);
        acc0 = __builtin_amdgcn_mfma_f32_16x16x32_bf16(ahi, bl0, acc0, 0, 0, 0);
        acc0 = __builtin_amdgcn_mfma_f32_16x16x32_bf16(alo, bh0, acc0, 0, 0, 0);
        acc1 = __builtin_amdgcn_mfma_f32_16x16x32_bf16(ahi, bh1, acc1, 0, 0, 0);
        acc1 = __builtin_amdgcn_mfma_f32_16x16x32_bf16(ahi, bl1, acc1, 0, 0, 0);
        acc1 = __builtin_amdgcn_mfma_f32_16x16x32_bf16(alo, bh1, acc1, 0, 0, 0);
    }
    float bias0 = Wb[o0 + m], bias1 = Wb[o0 + 16 + m];
    #pragma unroll
    for (int reg = 0; reg < 4; ++reg) {
        int row = quad * 4 + reg;
        whs[row][o0 + m] = acc0[reg] + bias0;
        whs[row][o0 + 16 + m] = acc1[reg] + bias1;
    }
    __syncthreads();
    {   // WhT writer: 2 threads per o, 8 n each
        int o = t >> 1, half = t & 1;
        u16x8 v8;
        #pragma unroll
        for (int r = 0; r < 8; ++r) v8[r] = (short)f2b(whs[half * 8 + r][o]);
        *(u16x8*)(WhT + (size_t)(b * FOUT + o) * NN + n0 + half * 8) = v8;
    }
    {   // e-dots + exp tables
        int outi = t >> 1, half = t & 1;
        int i = outi >> 3, d = outi & 7, hh = d & 3, side = d >> 2;
        const float* arow = attw + hh * (2 * FOUT) + side * FOUT + half * 64;
        float s = 0.f;
        #pragma unroll 8
        for (int k = 0; k < 64; ++k) s = fmaf(whs[i][half * 64 + k], arow[k], s);
        s += __shfl_xor(s, 1);
        if (half == 0) {
            float p = __expf(s), n = __expf(NEG_SLOPE * s);
            if (side == 0) {
                ELpair[(size_t)(b * NH + hh) * NN + n0 + i] = make_float2(p, n);
            } else {
                ERpk[((size_t)b * NN + n0 + i) * NH + hh] = packf16(p, n);
            }
        }
    }
}

// ---------------------------------------------------------------------------
// k_pack: adj (N x N int32) -> bitmask (N rows x 32 u64). Pure HBM stream.
// ---------------------------------------------------------------------------
__global__ __launch_bounds__(256) void k_pack(const int* __restrict__ adj,
                                              u64* __restrict__ mask) {
    int row = blockIdx.x;
    int wave = threadIdx.x >> 6, lane = threadIdx.x & 63;
    #pragma unroll
    for (int it = 0; it < 8; ++it) {
        int w = it * 4 + wave;
        int j = w * 64 + lane;
        u64 m = __ballot(adj[(size_t)row * NN + j] != 0);
        if (lane == 0) mask[row * 32 + w] = m;
    }
}

// ---------------------------------------------------------------------------
// kstat_t (transposed): lane = i, wave = b. NO cross-lane reduction.
//   sPartT[jp][b][h][i] = sum_{j in 64-chunk jp} bit(i,j)*max(elp*erp, eln*ern)
// Grid (NN/64, NN/64) = (32, 32) = 1024 blocks, 256 thr.
// mask: 1 coalesced u64 per lane; ER: same-address uint4 (HW broadcast),
// 8 cvts amortized over 64 lanes.
// ---------------------------------------------------------------------------
__global__ __launch_bounds__(256) void kstat_t(
    const unsigned int* __restrict__ ERpk, const float2* __restrict__ ELpair,
    const u64* __restrict__ mask, float* __restrict__ sPartT) {
    int lane = threadIdx.x & 63, b = threadIdx.x >> 6;
    int i = blockIdx.x * 64 + lane;
    int j0 = blockIdx.y * 64;
    u64 mw = mask[(size_t)i * 32 + (j0 >> 6)];
    float elp[NH], eln[NH], acc[NH];
    #pragma unroll
    for (int hh = 0; hh < NH; ++hh) {
        float2 e2 = ELpair[(size_t)(b * NH + hh) * NN + i];
        elp[hh] = e2.x; eln[hh] = e2.y; acc[hh] = 0.f;
    }
    const uint4* erb = (const uint4*)(ERpk + ((size_t)b * NN + j0) * NH);
    #pragma unroll 8
    for (int jj = 0; jj < 64; ++jj) {
        uint4 er4 = erb[jj];               // wave-broadcast load
        bool bit = (mw >> jj) & 1ull;
        float m0 = fmaxf(elp[0] * f16lo(er4.x), eln[0] * f16hi(er4.x));
        float m1 = fmaxf(elp[1] * f16lo(er4.y), eln[1] * f16hi(er4.y));
        float m2 = fmaxf(elp[2] * f16lo(er4.z), eln[2] * f16hi(er4.z));
        float m3 = fmaxf(elp[3] * f16lo(er4.w), eln[3] * f16hi(er4.w));
        acc[0] += bit ? m0 : 0.f;
        acc[1] += bit ? m1 : 0.f;
        acc[2] += bit ? m2 : 0.f;
        acc[3] += bit ? m3 : 0.f;
    }
    #pragma unroll
    for (int hh = 0; hh < NH; ++hh)
        sPartT[(((size_t)blockIdx.y * BB + b) * NH + hh) * NN + i] = acc[hh];
}

// ---------------------------------------------------------------------------
// K2b: P[jhalf][b,i,o] = sum_{j in half} w[i,j] * Wh[b,j,o], MFMA 16x16x32.
// Block = 512 thr (8 waves), TI=64 i-rows, all 128 o, 1024 j (one half).
// Prologue: sum 32 sPartT partials -> inv -> inv-scaled EL pairs in LDS.
// ---------------------------------------------------------------------------
__global__ __launch_bounds__(512, 2) void k2b_mfma(
    const unsigned short* __restrict__ WhT, const unsigned int* __restrict__ ERpk,
    const float2* __restrict__ ELpair, const float* __restrict__ sPartT,
    const u64* __restrict__ mask, float* __restrict__ P) {
    __shared__ unsigned short wt[64][264];    // 33.8 KB bf16 w-tile
    __shared__ u64 mws[64][16];               // 8 KB
    __shared__ float elsc_s[64][8];           // 2 KB
    int t = threadIdx.x;
    int b = blockIdx.y, i0 = blockIdx.x * 64, jhalf = blockIdx.z;
    int lane = t & 63, wv = t >> 6;
    int m = lane & 15, quad = lane >> 4;
    if (t < 256) {                            // (i = t&63, h = t>>6)
        int li = t & 63, hh = t >> 6;
        float s = 0.f;
        #pragma unroll
        for (int jp = 0; jp < 32; ++jp)
            s += sPartT[(((size_t)jp * BB + b) * NH + hh) * NN + i0 + li];
        float iv = (s > 0.f) ? 0.25f / s : 0.f;
        float2 e2 = ELpair[(size_t)(b * NH + hh) * NN + i0 + li];
        elsc_s[li][hh * 2]     = e2.x * iv;
        elsc_s[li][hh * 2 + 1] = e2.y * iv;
    }
    {
        int r = t >> 3, wp = (t & 7) * 2;
        *(ulonglong2*)&mws[r][wp] =
            *(const ulonglong2*)(mask + (size_t)(i0 + r) * 32 + jhalf * 16 + wp);
    }
    int r0 = wv * 8;
    int o0 = wv * 16;
    const unsigned short* bp = WhT + (size_t)(b * FOUT + o0 + m) * NN + jhalf * 1024;
    f32x4 acc[4];
    #pragma unroll
    for (int k = 0; k < 4; ++k) acc[k] = (f32x4){0.f, 0.f, 0.f, 0.f};

    for (int ch = 0; ch < 4; ++ch) {
        int j0 = ch * 256;
        __syncthreads();
        bf16x8 bfr[8];
        #pragma unroll
        for (int ks = 0; ks < 8; ++ks)
            bfr[ks] = *(const bf16x8*)(bp + j0 + ks * 32 + quad * 8);
        float erp[4][4], ern[4][4];
        #pragma unroll
        for (int q = 0; q < 4; ++q) {
            int jg = jhalf * 1024 + j0 + q * 64 + lane;
            uint4 er4 = *(const uint4*)(ERpk + ((size_t)b * NN + jg) * 4);
            erp[q][0] = f16lo(er4.x); ern[q][0] = f16hi(er4.x);
            erp[q][1] = f16lo(er4.y); ern[q][1] = f16hi(er4.y);
            erp[q][2] = f16lo(er4.z); ern[q][2] = f16hi(er4.z);
            erp[q][3] = f16lo(er4.w); ern[q][3] = f16hi(er4.w);
        }
        #pragma unroll
        for (int r = 0; r < 8; ++r) {
            int ir = r0 + r;
            float4 c0 = *(float4*)&elsc_s[ir][0];
            float4 c1 = *(float4*)&elsc_s[ir][4];
            u64 mwq[4] = {mws[ir][ch * 4 + 0], mws[ir][ch * 4 + 1],
                          mws[ir][ch * 4 + 2], mws[ir][ch * 4 + 3]};
            #pragma unroll
            for (int q = 0; q < 4; ++q) {
                float p = fmaxf(c0.x * erp[q][0], c0.y * ern[q][0]);
                p += fmaxf(c0.z * erp[q][1], c0.w * ern[q][1]);
                p += fmaxf(c1.x * erp[q][2], c1.y * ern[q][2]);
                p += fmaxf(c1.z * erp[q][3], c1.w * ern[q][3]);
                wt[ir][q * 64 + lane] = ((mwq[q] >> lane) & 1ull) ? f2b_fast(p) : 0;
            }
        }
        __syncthreads();
        #pragma unroll
        for (int isub = 0; isub < 4; ++isub) {
            #pragma unroll
            for (int ks = 0; ks < 8; ++ks) {
                bf16x8 a = *(bf16x8*)&wt[isub * 16 + m][ks * 32 + quad * 8];
                acc[isub] = __builtin_amdgcn_mfma_f32_16x16x32_bf16(a, bfr[ks], acc[isub], 0, 0, 0);
            }
        }
    }
    float* pb = P + (((size_t)jhalf * BB + b) * NN + i0) * FOUT;
    #pragma unroll
    for (int isub = 0; isub < 4; ++isub) {
        #pragma unroll
        for (int reg = 0; reg < 4; ++reg) {
            int row = isub * 16 + quad * 4 + reg;
            pb[(size_t)row * FOUT + o0 + m] = acc[isub][reg];
        }
    }
}

// ---------------------------------------------------------------------------
// K3: out = relu(P0 + P1)
// ---------------------------------------------------------------------------
__global__ __launch_bounds__(256) void k3_relu(const float* __restrict__ P,
                                               float* __restrict__ out) {
    int idx = blockIdx.x * 256 + threadIdx.x;
    float4 a = ((const float4*)P)[idx];
    float4 c = ((const float4*)P)[idx + (BB * NN * FOUT / 4)];
    a.x = fmaxf(a.x + c.x, 0.f); a.y = fmaxf(a.y + c.y, 0.f);
    a.z = fmaxf(a.z + c.z, 0.f); a.w = fmaxf(a.w + c.w, 0.f);
    ((float4*)out)[idx] = a;
}

extern "C" void kernel_launch(void* const* d_in, const int* in_sizes, int n_in,
                              void* d_out, int out_size, void* d_ws, size_t ws_size,
                              hipStream_t stream) {
    const float* h    = (const float*)d_in[0];
    const int* adj    = (const int*)d_in[1];
    const float* Ww   = (const float*)d_in[2];
    const float* Wb   = (const float*)d_in[3];
    const float* attw = (const float*)d_in[4];
    float* out = (float*)d_out;
    char* ws = (char*)d_ws;
    // workspace layout (~15.8 MB)
    unsigned short* Whi = (unsigned short*)(ws);                 // 64 KB
    unsigned short* Wlo = (unsigned short*)(ws + 65536);         // 64 KB
    unsigned short* WhT = (unsigned short*)(ws + 131072);        // 2 MB [b][o][n] bf16
    float2*       ELpair = (float2*)(ws + 2228224);              // 256 KB [bh][i]
    unsigned int* ERpk   = (unsigned int*)(ws + 2490368);        // 128 KB [b][j][h] f16pk
    u64*          mask   = (u64*)(ws + 2621440);                 // 512 KB
    float*        sPartT = (float*)(ws + 3145728);               // 4 MB [jp][b][h][i]
    float*        P      = (float*)(ws + 7340032);               // 2 x 4 MB partials

    kcvt_w<<<dim3(128), dim3(256), 0, stream>>>(Ww, Whi, Wlo);
    k1_wh<<<dim3(BB * NN / 16), dim3(256), 0, stream>>>(h, Whi, Wlo, Wb, attw,
                                                        WhT, ELpair, ERpk);
    k_pack<<<dim3(NN), dim3(256), 0, stream>>>(adj, mask);
    kstat_t<<<dim3(NN / 64, NN / 64), dim3(256), 0, stream>>>(ERpk, ELpair, mask, sPartT);
    k2b_mfma<<<dim3(NN / 64, BB, 2), dim3(512), 0, stream>>>(WhT, ERpk, ELpair,
                                                             sPartT, mask, P);
    k3_relu<<<dim3(BB * NN * FOUT / 1024), dim3(256), 0, stream>>>(P, out);
}

// Round 9
// 132.070 us; speedup vs baseline: 1.2706x; 1.0388x over previous
//
#include <hip/hip_runtime.h>
#include <stdint.h>

#define BB 4
#define NN 2048
#define FIN 256
#define FOUT 128
#define NH 4
#define NEG_SLOPE 0.2f

typedef short bf16x8 __attribute__((ext_vector_type(8)));
typedef unsigned short u16x8 __attribute__((ext_vector_type(8)));
typedef float f32x4 __attribute__((ext_vector_type(4)));
typedef unsigned long long u64;

__device__ inline float b2f(unsigned short u) {
    union { unsigned int i; float f; } x; x.i = ((unsigned int)u) << 16; return x.f;
}
__device__ inline unsigned short f2b(float f) {   // fp32 -> bf16 RNE
    union { float f; unsigned int i; } x; x.f = f;
    unsigned int r = x.i + 0x7fffu + ((x.i >> 16) & 1u);
    return (unsigned short)(r >> 16);
}
__device__ inline unsigned short f2b_fast(float f) {  // round-half-up (f >= 0 here)
    union { float f; unsigned int i; } x; x.f = f;
    return (unsigned short)((x.i + 0x8000u) >> 16);
}
union F16U { unsigned short u; _Float16 h; };
__device__ inline float f16lo(unsigned int v) { F16U x; x.u = (unsigned short)(v & 0xffffu); return (float)x.h; }
__device__ inline float f16hi(unsigned int v) { F16U x; x.u = (unsigned short)(v >> 16); return (float)x.h; }
__device__ inline unsigned int packf16(float a, float b) {
    F16U x, y; x.h = (_Float16)a; y.h = (_Float16)b;
    return (unsigned int)x.u | ((unsigned int)y.u << 16);
}

// ---------------------------------------------------------------------------
// kcvtW: split W fp32 -> bf16 hi/lo pair
// ---------------------------------------------------------------------------
__global__ __launch_bounds__(256) void kcvt_w(const float* __restrict__ Ww,
                                              unsigned short* __restrict__ Whi,
                                              unsigned short* __restrict__ Wlo) {
    int idx = blockIdx.x * 256 + threadIdx.x;   // 32768 elems
    float v = Ww[idx];
    unsigned short hb = f2b(v);
    Whi[idx] = hb;
    Wlo[idx] = f2b(v - b2f(hb));
}

// ---------------------------------------------------------------------------
// K1 (MFMA): Wh[16 rows][128 o] = h_tile @ W^T + b, split-bf16 (hh+hl+lh).
// Epilogue: WhT bf16 [b][o][n]; exp tables:
//   ELpair[b*4+h][i] = (exp(eL), exp(0.2 eL)) fp32x2
//   ERpk  [b][j][h]  = packf16(exp(eR), exp(0.2 eR))
// ---------------------------------------------------------------------------
__global__ __launch_bounds__(256) void k1_wh(
    const float* __restrict__ h, const unsigned short* __restrict__ Whi,
    const unsigned short* __restrict__ Wlo, const float* __restrict__ Wb,
    const float* __restrict__ attw, unsigned short* __restrict__ WhT,
    float2* __restrict__ ELpair, unsigned int* __restrict__ ERpk) {
    __shared__ unsigned short Ahi[16][264];
    __shared__ unsigned short Alo[16][264];
    __shared__ float whs[16][132];
    int t = threadIdx.x;
    int b = blockIdx.x >> 7;
    int n0 = (blockIdx.x & 127) * 16;
    {
        int r = t >> 4, c = (t & 15) * 16;
        const float* hp = h + ((size_t)(b * NN + n0 + r)) * FIN + c;
        u16x8 hi0, hi1, lo0, lo1;
        #pragma unroll
        for (int q = 0; q < 4; ++q) {
            float4 v = *(const float4*)(hp + q * 4);
            float vv[4] = {v.x, v.y, v.z, v.w};
            #pragma unroll
            for (int e = 0; e < 4; ++e) {
                int idx = q * 4 + e;
                unsigned short hb = f2b(vv[e]);
                unsigned short lb = f2b(vv[e] - b2f(hb));
                if (idx < 8) { hi0[idx] = (short)hb; lo0[idx] = (short)lb; }
                else         { hi1[idx - 8] = (short)hb; lo1[idx - 8] = (short)lb; }
            }
        }
        *(u16x8*)&Ahi[r][c] = *(u16x8*)&hi0;
        *(u16x8*)&Ahi[r][c + 8] = *(u16x8*)&hi1;
        *(u16x8*)&Alo[r][c] = *(u16x8*)&lo0;
        *(u16x8*)&Alo[r][c + 8] = *(u16x8*)&lo1;
    }
    __syncthreads();
    int lane = t & 63, wv = t >> 6;
    int m = lane & 15, quad = lane >> 4;
    int o0 = wv * 32;
    f32x4 acc0 = {0.f, 0.f, 0.f, 0.f}, acc1 = {0.f, 0.f, 0.f, 0.f};
    const unsigned short* wh0 = Whi + (size_t)(o0 + m) * FIN;
    const unsigned short* wl0 = Wlo + (size_t)(o0 + m) * FIN;
    const unsigned short* wh1 = Whi + (size_t)(o0 + 16 + m) * FIN;
    const unsigned short* wl1 = Wlo + (size_t)(o0 + 16 + m) * FIN;
    #pragma unroll
    for (int ks = 0; ks < 8; ++ks) {
        int ko = ks * 32 + quad * 8;
        bf16x8 ahi = *(bf16x8*)&Ahi[m][ko];
        bf16x8 alo = *(bf16x8*)&Alo[m][ko];
        bf16x8 bh0 = *(const bf16x8*)(wh0 + ko);
        bf16x8 bl0 = *(const bf16x8*)(wl0 + ko);
        bf16x8 bh1 = *(const bf16x8*)(wh1 + ko);
        bf16x8 bl1 = *(const bf16x8*)(wl1 + ko);
        acc0 = __builtin_amdgcn_mfma_f32_16x16x32_bf16(ahi, bh0, acc0, 0, 0, 0);
        acc0 = __builtin_amdgcn_mfma_f32_16x16x32_bf16(ahi, bl0, acc0, 0, 0, 0);
        acc0 = __builtin_amdgcn_mfma_f32_16x16x32_bf16(alo, bh0, acc0, 0, 0, 0);
        acc1 = __builtin_amdgcn_mfma_f32_16x16x32_bf16(ahi, bh1, acc1, 0, 0, 0);
        acc1 = __builtin_amdgcn_mfma_f32_16x16x32_bf16(ahi, bl1, acc1, 0, 0, 0);
        acc1 = __builtin_amdgcn_mfma_f32_16x16x32_bf16(alo, bh1, acc1, 0, 0, 0);
    }
    float bias0 = Wb[o0 + m], bias1 = Wb[o0 + 16 + m];
    #pragma unroll
    for (int reg = 0; reg < 4; ++reg) {
        int row = quad * 4 + reg;
        whs[row][o0 + m] = acc0[reg] + bias0;
        whs[row][o0 + 16 + m] = acc1[reg] + bias1;
    }
    __syncthreads();
    {   // WhT writer: 2 threads per o, 8 n each
        int o = t >> 1, half = t & 1;
        u16x8 v8;
        #pragma unroll
        for (int r = 0; r < 8; ++r) v8[r] = (short)f2b(whs[half * 8 + r][o]);
        *(u16x8*)(WhT + (size_t)(b * FOUT + o) * NN + n0 + half * 8) = v8;
    }
    {   // e-dots + exp tables
        int outi = t >> 1, half = t & 1;
        int i = outi >> 3, d = outi & 7, hh = d & 3, side = d >> 2;
        const float* arow = attw + hh * (2 * FOUT) + side * FOUT + half * 64;
        float s = 0.f;
        #pragma unroll 8
        for (int k = 0; k < 64; ++k) s = fmaf(whs[i][half * 64 + k], arow[k], s);
        s += __shfl_xor(s, 1);
        if (half == 0) {
            float p = __expf(s), n = __expf(NEG_SLOPE * s);
            if (side == 0) {
                ELpair[(size_t)(b * NH + hh) * NN + n0 + i] = make_float2(p, n);
            } else {
                ERpk[((size_t)b * NN + n0 + i) * NH + hh] = packf16(p, n);
            }
        }
    }
}

// ---------------------------------------------------------------------------
// k_pack: adj (N x N int32) -> bitmask (N rows x 32 u64). Pure HBM stream.
// ---------------------------------------------------------------------------
__global__ __launch_bounds__(256) void k_pack(const int* __restrict__ adj,
                                              u64* __restrict__ mask) {
    int row = blockIdx.x;
    int wave = threadIdx.x >> 6, lane = threadIdx.x & 63;
    #pragma unroll
    for (int it = 0; it < 8; ++it) {
        int w = it * 4 + wave;
        int j = w * 64 + lane;
        u64 m = __ballot(adj[(size_t)row * NN + j] != 0);
        if (lane == 0) mask[row * 32 + w] = m;
    }
}

// ---------------------------------------------------------------------------
// kstat_t (transposed): lane = i, wave = b. NO cross-lane reduction.
//   sPartT[jp][b][h][i] = sum_{j in 64-chunk jp} bit(i,j)*max(elp*erp, eln*ern)
// ---------------------------------------------------------------------------
__global__ __launch_bounds__(256) void kstat_t(
    const unsigned int* __restrict__ ERpk, const float2* __restrict__ ELpair,
    const u64* __restrict__ mask, float* __restrict__ sPartT) {
    int lane = threadIdx.x & 63, b = threadIdx.x >> 6;
    int i = blockIdx.x * 64 + lane;
    int j0 = blockIdx.y * 64;
    u64 mw = mask[(size_t)i * 32 + (j0 >> 6)];
    float elp[NH], eln[NH], acc[NH];
    #pragma unroll
    for (int hh = 0; hh < NH; ++hh) {
        float2 e2 = ELpair[(size_t)(b * NH + hh) * NN + i];
        elp[hh] = e2.x; eln[hh] = e2.y; acc[hh] = 0.f;
    }
    const uint4* erb = (const uint4*)(ERpk + ((size_t)b * NN + j0) * NH);
    #pragma unroll 8
    for (int jj = 0; jj < 64; ++jj) {
        uint4 er4 = erb[jj];               // wave-broadcast load
        bool bit = (mw >> jj) & 1ull;
        float m0 = fmaxf(elp[0] * f16lo(er4.x), eln[0] * f16hi(er4.x));
        float m1 = fmaxf(elp[1] * f16lo(er4.y), eln[1] * f16hi(er4.y));
        float m2 = fmaxf(elp[2] * f16lo(er4.z), eln[2] * f16hi(er4.z));
        float m3 = fmaxf(elp[3] * f16lo(er4.w), eln[3] * f16hi(er4.w));
        acc[0] += bit ? m0 : 0.f;
        acc[1] += bit ? m1 : 0.f;
        acc[2] += bit ? m2 : 0.f;
        acc[3] += bit ? m3 : 0.f;
    }
    #pragma unroll
    for (int hh = 0; hh < NH; ++hh)
        sPartT[(((size_t)blockIdx.y * BB + b) * NH + hh) * NN + i] = acc[hh];
}

// ---------------------------------------------------------------------------
// K2b: P[jq][b,i,o] = sum_{j in quarter} w[i,j] * Wh[b,j,o], MFMA 16x16x32.
// Block = 512 thr (8 waves), TI=64 i-rows, all 128 o, 512 j (one quarter).
// Grid (32, 4, 4) = 512 blocks = 2/CU: phase A of one block overlaps phase B
// of the co-resident block (the R8 1-block/CU serialization fix).
// ---------------------------------------------------------------------------
__global__ __launch_bounds__(512, 4) void k2b_mfma(
    const unsigned short* __restrict__ WhT, const unsigned int* __restrict__ ERpk,
    const float2* __restrict__ ELpair, const float* __restrict__ sPartT,
    const u64* __restrict__ mask, float* __restrict__ P) {
    __shared__ unsigned short wt[64][264];    // 33.8 KB bf16 w-tile
    __shared__ u64 mws[64][8];                // 4 KB: this j-quarter's mask words
    __shared__ float elsc_s[64][8];           // 2 KB
    int t = threadIdx.x;
    int b = blockIdx.y, i0 = blockIdx.x * 64, jq = blockIdx.z;
    int lane = t & 63, wv = t >> 6;
    int m = lane & 15, quad = lane >> 4;
    if (t < 256) {                            // inv-scaled EL pairs (i = t&63, h = t>>6)
        int li = t & 63, hh = t >> 6;
        float s = 0.f;
        #pragma unroll
        for (int jp = 0; jp < 32; ++jp)
            s += sPartT[(((size_t)jp * BB + b) * NH + hh) * NN + i0 + li];
        float iv = (s > 0.f) ? 0.25f / s : 0.f;
        float2 e2 = ELpair[(size_t)(b * NH + hh) * NN + i0 + li];
        elsc_s[li][hh * 2]     = e2.x * iv;
        elsc_s[li][hh * 2 + 1] = e2.y * iv;
    }
    {   // stage this quarter's mask words: 64 rows x 8 u64
        int r = t >> 3, wp = t & 7;
        mws[r][wp] = mask[(size_t)(i0 + r) * 32 + jq * 8 + wp];
    }
    int r0 = wv * 8;
    int o0 = wv * 16;
    const unsigned short* bp = WhT + (size_t)(b * FOUT + o0 + m) * NN + jq * 512;
    f32x4 acc[4];
    #pragma unroll
    for (int k = 0; k < 4; ++k) acc[k] = (f32x4){0.f, 0.f, 0.f, 0.f};

    for (int ch = 0; ch < 2; ++ch) {
        int j0 = ch * 256;                    // within this quarter
        __syncthreads();
        bf16x8 bfr[8];
        #pragma unroll
        for (int ks = 0; ks < 8; ++ks)
            bfr[ks] = *(const bf16x8*)(bp + j0 + ks * 32 + quad * 8);
        float erp[4][4], ern[4][4];
        #pragma unroll
        for (int q = 0; q < 4; ++q) {
            int jg = jq * 512 + j0 + q * 64 + lane;
            uint4 er4 = *(const uint4*)(ERpk + ((size_t)b * NN + jg) * 4);
            erp[q][0] = f16lo(er4.x); ern[q][0] = f16hi(er4.x);
            erp[q][1] = f16lo(er4.y); ern[q][1] = f16hi(er4.y);
            erp[q][2] = f16lo(er4.z); ern[q][2] = f16hi(er4.z);
            erp[q][3] = f16lo(er4.w); ern[q][3] = f16hi(er4.w);
        }
        #pragma unroll
        for (int r = 0; r < 8; ++r) {
            int ir = r0 + r;
            float4 c0 = *(float4*)&elsc_s[ir][0];
            float4 c1 = *(float4*)&elsc_s[ir][4];
            u64 mwq[4] = {mws[ir][ch * 4 + 0], mws[ir][ch * 4 + 1],
                          mws[ir][ch * 4 + 2], mws[ir][ch * 4 + 3]};
            #pragma unroll
            for (int q = 0; q < 4; ++q) {
                float p = fmaxf(c0.x * erp[q][0], c0.y * ern[q][0]);
                p += fmaxf(c0.z * erp[q][1], c0.w * ern[q][1]);
                p += fmaxf(c1.x * erp[q][2], c1.y * ern[q][2]);
                p += fmaxf(c1.z * erp[q][3], c1.w * ern[q][3]);
                wt[ir][q * 64 + lane] = ((mwq[q] >> lane) & 1ull) ? f2b_fast(p) : 0;
            }
        }
        __syncthreads();
        #pragma unroll
        for (int isub = 0; isub < 4; ++isub) {
            #pragma unroll
            for (int ks = 0; ks < 8; ++ks) {
                bf16x8 a = *(bf16x8*)&wt[isub * 16 + m][ks * 32 + quad * 8];
                acc[isub] = __builtin_amdgcn_mfma_f32_16x16x32_bf16(a, bfr[ks], acc[isub], 0, 0, 0);
            }
        }
    }
    float* pb = P + (((size_t)jq * BB + b) * NN + i0) * FOUT;
    #pragma unroll
    for (int isub = 0; isub < 4; ++isub) {
        #pragma unroll
        for (int reg = 0; reg < 4; ++reg) {
            int row = isub * 16 + quad * 4 + reg;
            pb[(size_t)row * FOUT + o0 + m] = acc[isub][reg];
        }
    }
}

// ---------------------------------------------------------------------------
// K3: out = relu(P0 + P1 + P2 + P3)
// ---------------------------------------------------------------------------
__global__ __launch_bounds__(256) void k3_relu(const float* __restrict__ P,
                                               float* __restrict__ out) {
    int idx = blockIdx.x * 256 + threadIdx.x;
    const int slab = BB * NN * FOUT / 4;
    float4 a = ((const float4*)P)[idx];
    float4 c1 = ((const float4*)P)[idx + slab];
    float4 c2 = ((const float4*)P)[idx + 2 * slab];
    float4 c3 = ((const float4*)P)[idx + 3 * slab];
    a.x = fmaxf(a.x + c1.x + c2.x + c3.x, 0.f);
    a.y = fmaxf(a.y + c1.y + c2.y + c3.y, 0.f);
    a.z = fmaxf(a.z + c1.z + c2.z + c3.z, 0.f);
    a.w = fmaxf(a.w + c1.w + c2.w + c3.w, 0.f);
    ((float4*)out)[idx] = a;
}

extern "C" void kernel_launch(void* const* d_in, const int* in_sizes, int n_in,
                              void* d_out, int out_size, void* d_ws, size_t ws_size,
                              hipStream_t stream) {
    const float* h    = (const float*)d_in[0];
    const int* adj    = (const int*)d_in[1];
    const float* Ww   = (const float*)d_in[2];
    const float* Wb   = (const float*)d_in[3];
    const float* attw = (const float*)d_in[4];
    float* out = (float*)d_out;
    char* ws = (char*)d_ws;
    // workspace layout (~23.3 MB)
    unsigned short* Whi = (unsigned short*)(ws);                 // 64 KB
    unsigned short* Wlo = (unsigned short*)(ws + 65536);         // 64 KB
    unsigned short* WhT = (unsigned short*)(ws + 131072);        // 2 MB [b][o][n] bf16
    float2*       ELpair = (float2*)(ws + 2228224);              // 256 KB [bh][i]
    unsigned int* ERpk   = (unsigned int*)(ws + 2490368);        // 128 KB [b][j][h] f16pk
    u64*          mask   = (u64*)(ws + 2621440);                 // 512 KB
    float*        sPartT = (float*)(ws + 3145728);               // 4 MB [jp][b][h][i]
    float*        P      = (float*)(ws + 7340032);               // 4 x 4 MB partials

    kcvt_w<<<dim3(128), dim3(256), 0, stream>>>(Ww, Whi, Wlo);
    k1_wh<<<dim3(BB * NN / 16), dim3(256), 0, stream>>>(h, Whi, Wlo, Wb, attw,
                                                        WhT, ELpair, ERpk);
    k_pack<<<dim3(NN), dim3(256), 0, stream>>>(adj, mask);
    kstat_t<<<dim3(NN / 64, NN / 64), dim3(256), 0, stream>>>(ERpk, ELpair, mask, sPartT);
    k2b_mfma<<<dim3(NN / 64, BB, 4), dim3(512), 0, stream>>>(WhT, ERpk, ELpair,
                                                             sPartT, mask, P);
    k3_relu<<<dim3(BB * NN * FOUT / 1024), dim3(256), 0, stream>>>(P, out);
}